// Round 17
// baseline (494.688 us; speedup 1.0000x reference)
//
#include <hip/hip_runtime.h>

#define NN 50000
#define NPAD 50176         // padded rows (multiple of 128 and 64)
#define EE 100000
#define HIDD 128
#define HH 4
#define CCC 128
#define HCC 512
#define QS 2048            // row stride of fused qkvs buffer (u16 elements)
#define LLL 3
#define SCALE 0.08838834764831845f

typedef unsigned short u16;
typedef unsigned int u32;
typedef __attribute__((ext_vector_type(8))) short bfrag;   // 8 x bf16
typedef __attribute__((ext_vector_type(4))) float fx4;

__device__ __forceinline__ float bfl(u32 u){ return __uint_as_float(u << 16); }
__device__ __forceinline__ float bfh(u32 u){ return __uint_as_float(u & 0xffff0000u); }
__device__ __forceinline__ float bf1(u16 u){ return __uint_as_float((u32)u << 16); }
__device__ __forceinline__ u16 f2bf(float f){
  u32 u = __float_as_uint(f);
  return (u16)((u + 0x7fffu + ((u >> 16) & 1u)) >> 16);
}
__device__ __forceinline__ u32 pack2(float a, float b){
  return (u32)f2bf(a) | ((u32)f2bf(b) << 16);
}

union bfcvt { bfrag f; uint4 u; };

#if defined(__has_builtin)
#if __has_builtin(__builtin_amdgcn_global_load_lds)
#define USE_GLL 1
#endif
#endif
#ifndef USE_GLL
#define USE_GLL 0
#endif

// async global->LDS, 16B per lane. LDS dest: wave-uniform base + lane*16.
__device__ __forceinline__ void gll16(const u16* g, u16* l){
#if USE_GLL
  __builtin_amdgcn_global_load_lds(
      (const __attribute__((address_space(1))) unsigned int*)(const void*)g,
      (__attribute__((address_space(3))) unsigned int*)(void*)l, 16, 0, 0);
#else
  uint4 v = *(const uint4*)g;
  *(uint4*)l = v;
#endif
}

__global__ __launch_bounds__(256) void kzero(int* p, int n){
  int i = blockIdx.x * 256 + threadIdx.x;
  if (i < n) p[i] = 0;
}

// x f32 -> xb bf16 (padded rows zeroed)
__global__ __launch_bounds__(256) void kcvt(const float* __restrict__ x,
                                            u16* __restrict__ xb){
  int i = blockIdx.x * 256 + threadIdx.x;     // 4 elems per thread
  if (i >= NPAD*HIDD/4) return;
  int base = i * 4;
  uint2 o = make_uint2(0u, 0u);
  if (base < NN*HIDD) {
    float4 v = *(const float4*)(x + base);
    o = make_uint2(pack2(v.x,v.y), pack2(v.z,v.w));
  }
  *(uint2*)(xb + base) = o;
}

// ---------------- CSR build (once per launch) ----------------
__global__ __launch_bounds__(256) void khist(const int* __restrict__ ei, int* __restrict__ counts){
  int e = blockIdx.x * 256 + threadIdx.x;
  if (e < EE) atomicAdd(&counts[ei[EE + e]], 1);
}

__global__ __launch_bounds__(256) void kscanA(const int* __restrict__ counts, int* __restrict__ bsum){
  __shared__ int sh[256];
  int t = threadIdx.x, i = blockIdx.x * 256 + t;
  sh[t] = (i < NN) ? counts[i] : 0;
  __syncthreads();
  #pragma unroll
  for (int off = 128; off; off >>= 1) {
    if (t < off) sh[t] += sh[t + off];
    __syncthreads();
  }
  if (t == 0) bsum[blockIdx.x] = sh[0];
}

__global__ __launch_bounds__(256) void kscanB(int* __restrict__ bsum, int nb){
  __shared__ int sh[256];
  int t = threadIdx.x;
  int v = (t < nb) ? bsum[t] : 0;
  sh[t] = v;
  __syncthreads();
  #pragma unroll
  for (int off = 1; off < 256; off <<= 1) {
    int a = (t >= off) ? sh[t - off] : 0;
    __syncthreads();
    sh[t] += a;
    __syncthreads();
  }
  if (t < nb) bsum[t] = sh[t] - v;   // exclusive
}

__global__ __launch_bounds__(256) void kscanC(const int* __restrict__ counts,
                                              const int* __restrict__ bsum,
                                              int* __restrict__ rowptr){
  __shared__ int sh[256];
  int t = threadIdx.x, i = blockIdx.x * 256 + t;
  int v = (i < NN) ? counts[i] : 0;
  sh[t] = v;
  __syncthreads();
  #pragma unroll
  for (int off = 1; off < 256; off <<= 1) {
    int a = (t >= off) ? sh[t - off] : 0;
    __syncthreads();
    sh[t] += a;
    __syncthreads();
  }
  if (i <= NN) rowptr[i] = bsum[blockIdx.x] + sh[t] - v;
}

__global__ __launch_bounds__(256) void kscatter(const int* __restrict__ ei,
                                                const float* __restrict__ ea,
                                                const int* __restrict__ rowptr,
                                                int* __restrict__ fill,
                                                int* __restrict__ csr_src,
                                                float* __restrict__ csr_ea){
  int e = blockIdx.x * 256 + threadIdx.x;
  if (e >= EE) return;
  int d = ei[EE + e];
  int pos = rowptr[d] + atomicAdd(&fill[d], 1);
  csr_src[pos] = ei[e];
  csr_ea[pos]  = ea[e];
}

// ---------------- per-layer weight prep -----------------
// Wt[1536][128] bf16 (transposed [Wq|Wk|Wv]), Wpt[128][512] bf16, bias_cat[1536]
__global__ __launch_bounds__(256) void kprep(
    const float* __restrict__ Wq, const float* __restrict__ Wk,
    const float* __restrict__ Wv,
    const float* __restrict__ bq, const float* __restrict__ bk,
    const float* __restrict__ bv,
    const float* __restrict__ Wp,
    u16* __restrict__ Wt, u16* __restrict__ Wpt, float* __restrict__ bias_cat)
{
  int id = blockIdx.x * 256 + threadIdx.x;
  if (id < 1536*128) {
    int n = id >> 7, k = id & 127;
    int m = n >> 9, nc = n & 511;
    const float* W = (m==0)?Wq:(m==1)?Wk:Wv;
    Wt[id] = f2bf(W[(size_t)k*HCC + nc]);
  } else if (id < 1536*128 + 128*512) {
    int j = id - 1536*128;
    int n = j >> 9, k = j & 511;
    Wpt[j] = f2bf(Wp[(size_t)k*HIDD + n]);
  } else if (id < 1536*128 + 128*512 + 1536) {
    int n = id - (1536*128 + 128*512);
    int m = n >> 9, nc = n & 511;
    const float* b = (m==0)?bq:(m==1)?bk:bv;
    bias_cat[n] = b[nc];
  }
}

// kskp2 (MFMA): Wskt[b][a] = sum_j Wpt[b][j]*Wsk[a][j]  (= (Wsk@Wp)^T, bf16)
__global__ __launch_bounds__(256) void kskp2(
    const float* __restrict__ Wsk, const u16* __restrict__ Wpt,
    u16* __restrict__ Wskt)
{
  const int t = threadIdx.x;
  const int wave = t >> 6, lane = t & 63;
  const int lo = lane & 15, hi = lane >> 4;
  const int wr = wave >> 1, wc = wave & 1;
  const int b0 = blockIdx.x * 64 + wr * 32;
  const int a0 = blockIdx.y * 32 + wc * 16;

  fx4 acc[2] = {};
  #pragma unroll
  for (int kk = 0; kk < 16; ++kk) {
    const float* wp = Wsk + (size_t)(a0 + lo)*HCC + kk*32 + hi*8;
    float4 u = *(const float4*)(wp);
    float4 w = *(const float4*)(wp + 4);
    bfcvt bc;
    bc.u = make_uint4(pack2(u.x,u.y), pack2(u.z,u.w),
                      pack2(w.x,w.y), pack2(w.z,w.w));
    #pragma unroll
    for (int fr = 0; fr < 2; ++fr) {
      bfrag af = *(const bfrag*)(Wpt + (size_t)(b0 + fr*16 + lo)*HCC + kk*32 + hi*8);
      acc[fr] = __builtin_amdgcn_mfma_f32_16x16x32_bf16(af, bc.f, acc[fr], 0, 0, 0);
    }
  }
  #pragma unroll
  for (int fr = 0; fr < 2; ++fr)
    #pragma unroll
    for (int j = 0; j < 4; ++j)
      Wskt[(size_t)(b0 + fr*16 + hi*4 + j)*128 + a0 + lo] = f2bf(acc[fr][j]);
}

// kbpe: bpe[c] = bp[c] + sum_j bsk[j]*Wp[j][c]   (grid 4, parallel-reduced)
__global__ __launch_bounds__(256) void kbpe(
    const float* __restrict__ bsk, const float* __restrict__ Wp,
    const float* __restrict__ bp, float* __restrict__ bpe)
{
  __shared__ float part[8][32];
  const int c = blockIdx.x * 32 + (threadIdx.x & 31);
  const int seg = threadIdx.x >> 5;          // 0..7, 64 j's each
  float s = 0.f;
  #pragma unroll
  for (int j = 0; j < 64; ++j)
    s += bsk[seg*64 + j] * Wp[(size_t)(seg*64 + j)*HIDD + c];
  part[seg][threadIdx.x & 31] = s;
  __syncthreads();
  if (seg == 0) {
    float tot = bp[c];
    #pragma unroll
    for (int k = 0; k < 8; ++k) tot += part[k][threadIdx.x & 31];
    bpe[c] = tot;
  }
}

// K1: qkvs[N, 0..1536) = bf16( xb[N,128] @ Wt^T + bias )
// 128x128 tile/block, 4 waves (64x64), BK=32 x 4 steps double-buffered,
// stride-132 epilogue, bijective XCD-chunked swizzle.
__global__ __launch_bounds__(256) void k1_mfma(
    const u16* __restrict__ xb, const u16* __restrict__ Wt,
    const float* __restrict__ bias, u16* __restrict__ qkvs)
{
  __shared__ u16 lds[16896];
  const int t = threadIdx.x;
  const int wave = t >> 6, lane = t & 63;
  const int lo = lane & 15, hi = lane >> 4;
  const int wr = wave >> 1, wc = wave & 1;

  int b = blockIdx.x;
  const int qq = 4692/8, rr = 4692%8;     // 586, 4
  int xcd = b & 7, slot = b >> 3;
  int wgid = (xcd < rr ? xcd*(qq+1) : rr*(qq+1) + (xcd-rr)*qq) + slot;
  const int rb = (wgid / 12) * 128;
  const int cb = (wgid % 12) * 128;

  auto STAGE = [&](int buf, int kk){
    #pragma unroll
    for (int half = 0; half < 2; ++half) {
      int c = wave*64 + lane + half*256;
      int row = c >> 2, seg = c & 3;
      gll16(xb + (size_t)(rb + row)*HIDD + kk*32 + seg*8,
            &lds[buf*4096 + (wave*64 + half*256)*8]);
    }
    #pragma unroll
    for (int half = 0; half < 2; ++half) {
      int c = wave*64 + lane + half*256;
      int row = c >> 2, seg = c & 3;
      gll16(Wt + (size_t)(cb + row)*HIDD + kk*32 + seg*8,
            &lds[8192 + buf*4096 + (wave*64 + half*256)*8]);
    }
  };

#if !USE_GLL
  auto STAGE_REG = [&](int buf, int kk){
    #pragma unroll
    for (int half = 0; half < 2; ++half) {
      int c = wave*64 + lane + half*256;
      int row = c >> 2, seg = c & 3;
      uint4 v = *(const uint4*)(xb + (size_t)(rb + row)*HIDD + kk*32 + seg*8);
      *(uint4*)&lds[buf*4096 + c*8] = v;
      uint4 w = *(const uint4*)(Wt + (size_t)(cb + row)*HIDD + kk*32 + seg*8);
      *(uint4*)&lds[8192 + buf*4096 + c*8] = w;
    }
  };
#define DO_STAGE STAGE_REG
#else
#define DO_STAGE STAGE
#endif

  fx4 acc[4][4] = {};

  DO_STAGE(0, 0);
  __syncthreads();
  #pragma unroll
  for (int kk = 0; kk < 4; ++kk) {
    const int buf = kk & 1;
    if (kk < 3) DO_STAGE(buf ^ 1, kk + 1);
    bfrag a[4], b2[4];
    #pragma unroll
    for (int fr = 0; fr < 4; ++fr)
      a[fr] = *(const bfrag*)&lds[buf*4096 + (wr*64 + fr*16 + lo)*32 + hi*8];
    #pragma unroll
    for (int fc = 0; fc < 4; ++fc)
      b2[fc] = *(const bfrag*)&lds[8192 + buf*4096 + (wc*64 + fc*16 + lo)*32 + hi*8];
    #pragma unroll
    for (int fr = 0; fr < 4; ++fr)
      #pragma unroll
      for (int fc = 0; fc < 4; ++fc)
        acc[fr][fc] = __builtin_amdgcn_mfma_f32_16x16x32_bf16(a[fr], b2[fc], acc[fr][fc], 0, 0, 0);
    __syncthreads();
  }

  float bb[4];
  #pragma unroll
  for (int fc = 0; fc < 4; ++fc) bb[fc] = bias[cb + wc*64 + fc*16 + lo];
  #pragma unroll
  for (int fr = 0; fr < 4; ++fr)
    #pragma unroll
    for (int fc = 0; fc < 4; ++fc)
      #pragma unroll
      for (int j = 0; j < 4; ++j)
        lds[(size_t)(wr*64 + fr*16 + hi*4 + j)*132 + wc*64 + fc*16 + lo]
            = f2bf(acc[fr][fc][j] + bb[fc]);
  __syncthreads();

  #pragma unroll
  for (int i = 0; i < 8; ++i) {
    int f = t + 256*i;
    int row = f >> 4, seg = f & 15;
    if (rb + row < NN)
      *(uint4*)(qkvs + (size_t)(rb+row)*QS + cb + seg*8) = *(uint4*)&lds[(size_t)row*132 + seg*8];
  }
}

// K23: fused edge attention per dst node (one wave per node).
__global__ __launch_bounds__(256) void k23_fused(
    u16* __restrict__ qkvs, const int* __restrict__ rowptr,
    const int* __restrict__ csr_src, const float* __restrict__ csr_ea,
    const float* __restrict__ We)
{
  int wave = threadIdx.x >> 6, lane = threadIdx.x & 63;
  int n = blockIdx.x * 4 + wave;
  if (n >= NN) return;
  int h = lane >> 4, c0 = (lane & 15) * 8;

  uint4 qa = *(const uint4*)(qkvs + (size_t)n*QS + h*CCC + c0);
  float qf[8] = {bfl(qa.x),bfh(qa.x),bfl(qa.y),bfh(qa.y),
                 bfl(qa.z),bfh(qa.z),bfl(qa.w),bfh(qa.w)};
  float4 w0 = *(const float4*)(We + h*CCC + c0);
  float4 w1 = *(const float4*)(We + h*CCC + c0 + 4);
  float wf[8] = {w0.x,w0.y,w0.z,w0.w,w1.x,w1.y,w1.z,w1.w};

  float qw = qf[0]*wf[0]+qf[1]*wf[1]+qf[2]*wf[2]+qf[3]*wf[3]
           + qf[4]*wf[4]+qf[5]*wf[5]+qf[6]*wf[6]+qf[7]*wf[7];
  #pragma unroll
  for (int off = 8; off; off >>= 1) qw += __shfl_xor(qw, off);

  int beg = rowptr[n], end = rowptr[n+1];
  float accv[8] = {};
  float accp = 0.f, accw = 0.f;

  for (int i = beg; i < end; ++i) {
    int src = csr_src[i];
    float eav = csr_ea[i];
    uint4 ka = *(const uint4*)(qkvs + (size_t)src*QS + 512 + h*CCC + c0);
    float s = qf[0]*bfl(ka.x) + qf[1]*bfh(ka.x)
            + qf[2]*bfl(ka.y) + qf[3]*bfh(ka.y)
            + qf[4]*bfl(ka.z) + qf[5]*bfh(ka.z)
            + qf[6]*bfl(ka.w) + qf[7]*bfh(ka.w);
    #pragma unroll
    for (int off = 8; off; off >>= 1) s += __shfl_xor(s, off);
    float p = expf((s + eav * qw) * SCALE);
    uint4 va = *(const uint4*)(qkvs + (size_t)src*QS + 1024 + h*CCC + c0);
    accv[0] += p*bfl(va.x); accv[1] += p*bfh(va.x);
    accv[2] += p*bfl(va.y); accv[3] += p*bfh(va.y);
    accv[4] += p*bfl(va.z); accv[5] += p*bfh(va.z);
    accv[6] += p*bfl(va.w); accv[7] += p*bfh(va.w);
    accp += p; accw += p*eav;
  }

  float inv = 1.f / (accp + 1e-16f);
  float se  = accw * inv;
  u16* ap = qkvs + (size_t)n*QS + 1536 + h*CCC + c0;
  *(uint4*)ap = make_uint4(
    pack2(accv[0]*inv+se*wf[0], accv[1]*inv+se*wf[1]),
    pack2(accv[2]*inv+se*wf[2], accv[3]*inv+se*wf[3]),
    pack2(accv[4]*inv+se*wf[4], accv[5]*inv+se*wf[5]),
    pack2(accv[6]*inv+se*wf[6], accv[7]*inv+se*wf[7]));
}

// K4 (fused K=640, register epilogue): y = elu([conv|xb]@[Wpt;Wskt]+bpe) + xb ; LN
// 64x128 tile, 4 waves 2x2 (32x64, acc 2x4), BK=32 x 20 steps double-buffered.
// Residual from bf16 xb; LN stats in-register + 1KB cross-wave partials;
// writes bf16 xb_out always, f32 x_out only when last=1.
__global__ __launch_bounds__(256) void k4_mfma(
    const u16* __restrict__ qkvs, const u16* __restrict__ xb_in,
    const u16* __restrict__ Wpt, const u16* __restrict__ Wskt,
    const float* __restrict__ bpe,
    const float* __restrict__ gamma, const float* __restrict__ beta,
    float* __restrict__ x_out, u16* __restrict__ xb_out, int last)
{
  __shared__ u16 lds[12288];     // A [2][2048] at 0, B [2][4096] at 4096
  __shared__ float ps[64][2], ps2[64][2];
  const int t = threadIdx.x;
  const int wave = t >> 6, lane = t & 63;
  const int lo = lane & 15, hi = lane >> 4;
  const int wr = wave >> 1, wc = wave & 1;
  const int rb = blockIdx.x * 64;

  auto STAGE = [&](int buf, int kk){
    {
      int c = wave*64 + lane;                   // 256 chunks: 64 rows x 4 segs
      int row = c >> 2, seg = c & 3;
      const u16* src = (kk < 16)
        ? qkvs + (size_t)(rb + row)*QS + 1536 + kk*32 + seg*8
        : xb_in + (size_t)(rb + row)*HIDD + (kk-16)*32 + seg*8;
#if USE_GLL
      gll16(src, &lds[buf*2048 + (wave*64)*8]);
#else
      *(uint4*)&lds[buf*2048 + c*8] = *(const uint4*)src;
#endif
    }
    #pragma unroll
    for (int half = 0; half < 2; ++half) {      // 512 chunks: 128 cols x 4 segs
      int c = wave*64 + lane + half*256;
      int col = c >> 2, seg = c & 3;
      const u16* src = (kk < 16)
        ? Wpt  + (size_t)col*512 + kk*32 + seg*8
        : Wskt + (size_t)col*128 + (kk-16)*32 + seg*8;
#if USE_GLL
      gll16(src, &lds[4096 + buf*4096 + (wave*64 + half*256)*8]);
#else
      *(uint4*)&lds[4096 + buf*4096 + c*8] = *(const uint4*)src;
#endif
    }
  };

  fx4 acc[2][4] = {};

  STAGE(0, 0);
  __syncthreads();
  #pragma unroll
  for (int kk = 0; kk < 20; ++kk) {
    const int buf = kk & 1;
    if (kk < 19) STAGE(buf ^ 1, kk + 1);
    bfrag a[2], b[4];
    #pragma unroll
    for (int fr = 0; fr < 2; ++fr)
      a[fr] = *(const bfrag*)&lds[buf*2048 + (wr*32 + fr*16 + lo)*32 + hi*8];
    #pragma unroll
    for (int fc = 0; fc < 4; ++fc)
      b[fc] = *(const bfrag*)&lds[4096 + buf*4096 + (wc*64 + fc*16 + lo)*32 + hi*8];
    #pragma unroll
    for (int fr = 0; fr < 2; ++fr)
      #pragma unroll
      for (int fc = 0; fc < 4; ++fc)
        acc[fr][fc] = __builtin_amdgcn_mfma_f32_16x16x32_bf16(a[fr], b[fc], acc[fr][fc], 0, 0, 0);
    __syncthreads();
  }

  // epilogue fully in-register: bias + ELU + bf16 residual
  // thread's rows: r = wr*32 + fr*16 + hi*4 + j ; cols: wc*64 + fc*16 + lo
  float y[2][4][4];
  #pragma unroll
  for (int fc = 0; fc < 4; ++fc) {
    int col = wc*64 + fc*16 + lo;
    float bb = bpe[col];
    #pragma unroll
    for (int fr = 0; fr < 2; ++fr)
      #pragma unroll
      for (int j = 0; j < 4; ++j) {
        int row = rb + wr*32 + fr*16 + hi*4 + j;
        float v = acc[fr][fc][j] + bb;
        v = v > 0.f ? v : expm1f(v);
        float xv = (row < NN) ? bf1(xb_in[(size_t)row*HIDD + col]) : 0.f;
        y[fr][fc][j] = xv + v;
      }
  }

  // row partial sums over this wave's 64 cols: reduce 4 fc then 16 lo lanes
  #pragma unroll
  for (int fr = 0; fr < 2; ++fr)
    #pragma unroll
    for (int j = 0; j < 4; ++j) {
      float s  = y[fr][0][j] + y[fr][1][j] + y[fr][2][j] + y[fr][3][j];
      float s2 = y[fr][0][j]*y[fr][0][j] + y[fr][1][j]*y[fr][1][j]
               + y[fr][2][j]*y[fr][2][j] + y[fr][3][j]*y[fr][3][j];
      #pragma unroll
      for (int off = 8; off; off >>= 1) { s += __shfl_xor(s, off); s2 += __shfl_xor(s2, off); }
      if (lo == 0) {
        int r = wr*32 + fr*16 + hi*4 + j;
        ps[r][wc] = s; ps2[r][wc] = s2;
      }
    }
  __syncthreads();

  // normalize + store (bf16 always; f32 only on last layer)
  #pragma unroll
  for (int fr = 0; fr < 2; ++fr)
    #pragma unroll
    for (int j = 0; j < 4; ++j) {
      int r = wr*32 + fr*16 + hi*4 + j;
      int row = rb + r;
      if (row >= NN) continue;
      float s  = ps[r][0] + ps[r][1];
      float s2 = ps2[r][0] + ps2[r][1];
      float mu = s * (1.f/128.f);
      float var = s2 * (1.f/128.f) - mu*mu;
      float rs = rsqrtf(var + 1e-5f);
      #pragma unroll
      for (int fc = 0; fc < 4; ++fc) {
        int col = wc*64 + fc*16 + lo;
        float o = (y[fr][fc][j] - mu)*rs*gamma[col] + beta[col];
        xb_out[(size_t)row*HIDD + col] = f2bf(o);
        if (last) x_out[(size_t)row*HIDD + col] = o;
      }
    }
}

extern "C" void kernel_launch(void* const* d_in, const int* in_sizes, int n_in,
                              void* d_out, int out_size, void* d_ws, size_t ws_size,
                              hipStream_t stream)
{
  const float* x    = (const float*)d_in[0];
  const int*   ei   = (const int*)d_in[1];
  const float* ea   = (const float*)d_in[2];
  const float* Wq   = (const float*)d_in[3];
  const float* bq   = (const float*)d_in[4];
  const float* Wk   = (const float*)d_in[5];
  const float* bk   = (const float*)d_in[6];
  const float* Wv   = (const float*)d_in[7];
  const float* bv   = (const float*)d_in[8];
  const float* We   = (const float*)d_in[9];
  const float* Wsk  = (const float*)d_in[10];
  const float* bsk  = (const float*)d_in[11];
  const float* Wp   = (const float*)d_in[12];
  const float* bp   = (const float*)d_in[13];
  const float* gamma= (const float*)d_in[14];
  const float* beta = (const float*)d_in[15];

  char* wsb = (char*)d_ws;
  size_t off = 0;
  auto alloc = [&](size_t bytes) -> void* {
    void* p = wsb + off;
    off += (bytes + 255) & ~(size_t)255;
    return p;
  };
  u16*   qkvs    = (u16*)  alloc((size_t)NPAD*QS*2);   // 205.5 MB (q|k|v|conv, padded)
  u16*   xb      = (u16*)  alloc((size_t)NPAD*HIDD*2); // 12.85 MB bf16 x
  int*   rowptr  = (int*)  alloc((size_t)(NN+1)*4);
  int*   counts  = (int*)  alloc((size_t)NN*4);
  int*   fill    = (int*)  alloc((size_t)NN*4);
  int*   bsum    = (int*)  alloc((size_t)256*4);
  int*   csr_src = (int*)  alloc((size_t)EE*4);
  float* csr_ea  = (float*)alloc((size_t)EE*4);
  u16*   Wt      = (u16*)  alloc((size_t)1536*128*2);
  u16*   Wpt     = (u16*)  alloc((size_t)128*512*2);
  u16*   Wskt    = (u16*)  alloc((size_t)128*128*2);
  float* biasc   = (float*)alloc((size_t)1536*4);
  float* bpe     = (float*)alloc((size_t)128*4);
  float* xio     = (float*)d_out;

  const int gn  = (NN + 255)/256;     // 196
  const int ge  = (EE + 255)/256;
  const int gp  = (1536*128 + 128*512 + 1536 + 255)/256;
  const int gc  = (NPAD*HIDD/4 + 255)/256;   // kcvt
  const int g1  = 12 * ((NN + 127)/128);     // 4692 blocks, swizzled in-kernel
  const dim3 gsk(2, 4);               // kskp2 tiles
  const int g23 = (NN + 3)/4;
  const int g4  = NPAD/64;            // 784 blocks of 64 rows

  // ---- CSR build (graph constant across layers) + x bf16 ----
  kzero<<<gn, 256, 0, stream>>>(counts, NN);
  kzero<<<gn, 256, 0, stream>>>(fill, NN);
  khist<<<ge, 256, 0, stream>>>(ei, counts);
  kscanA<<<gn, 256, 0, stream>>>(counts, bsum);
  kscanB<<<1, 256, 0, stream>>>(bsum, gn);
  kscanC<<<gn, 256, 0, stream>>>(counts, bsum, rowptr);
  kscatter<<<ge, 256, 0, stream>>>(ei, ea, rowptr, fill, csr_src, csr_ea);
  kcvt<<<gc, 256, 0, stream>>>(x, xb);

  for (int l = 0; l < LLL; ++l) {
    const float* Wq_l  = Wq  + (size_t)l*HIDD*HCC;
    const float* Wk_l  = Wk  + (size_t)l*HIDD*HCC;
    const float* Wv_l  = Wv  + (size_t)l*HIDD*HCC;
    const float* Wsk_l = Wsk + (size_t)l*HIDD*HCC;
    const float* bq_l  = bq  + (size_t)l*HCC;
    const float* bk_l  = bk  + (size_t)l*HCC;
    const float* bv_l  = bv  + (size_t)l*HCC;
    const float* bsk_l = bsk + (size_t)l*HCC;
    const float* We_l  = We  + (size_t)l*HCC;
    const float* Wp_l  = Wp  + (size_t)l*HCC*HIDD;
    const float* bp_l  = bp  + (size_t)l*HIDD;
    const float* g_l   = gamma + (size_t)l*HIDD;
    const float* b_l   = beta  + (size_t)l*HIDD;

    kprep<<<gp, 256, 0, stream>>>(Wq_l, Wk_l, Wv_l, bq_l, bk_l, bv_l,
                                  Wp_l, Wt, Wpt, biasc);
    kskp2<<<gsk, 256, 0, stream>>>(Wsk_l, Wpt, Wskt);
    kbpe<<<4, 256, 0, stream>>>(bsk_l, Wp_l, bp_l, bpe);
    k1_mfma<<<g1, 256, 0, stream>>>(xb, Wt, biasc, qkvs);
    k23_fused<<<g23, 256, 0, stream>>>(qkvs, rowptr, csr_src, csr_ea, We_l);
    k4_mfma<<<g4, 256, 0, stream>>>(qkvs, xb, Wpt, Wskt, bpe, g_l, b_l,
                                    xio, xb, (l == LLL-1) ? 1 : 0);
  }
}

// Round 18
// 446.080 us; speedup vs baseline: 1.1090x; 1.1090x over previous
//
#include <hip/hip_runtime.h>

#define NN 50000
#define NPAD 50176         // padded rows (multiple of 128 and 64)
#define EE 100000
#define HIDD 128
#define HH 4
#define CCC 128
#define HCC 512
#define QS 2048            // row stride of fused qkvs buffer (u16 elements)
#define LLL 3
#define SCALE 0.08838834764831845f

typedef unsigned short u16;
typedef unsigned int u32;
typedef __attribute__((ext_vector_type(8))) short bfrag;   // 8 x bf16
typedef __attribute__((ext_vector_type(4))) float fx4;

__device__ __forceinline__ float bfl(u32 u){ return __uint_as_float(u << 16); }
__device__ __forceinline__ float bfh(u32 u){ return __uint_as_float(u & 0xffff0000u); }
__device__ __forceinline__ float bf1(u16 u){ return __uint_as_float((u32)u << 16); }
__device__ __forceinline__ u16 f2bf(float f){
  u32 u = __float_as_uint(f);
  return (u16)((u + 0x7fffu + ((u >> 16) & 1u)) >> 16);
}
__device__ __forceinline__ u32 pack2(float a, float b){
  return (u32)f2bf(a) | ((u32)f2bf(b) << 16);
}

union bfcvt { bfrag f; uint4 u; };

#if defined(__has_builtin)
#if __has_builtin(__builtin_amdgcn_global_load_lds)
#define USE_GLL 1
#endif
#endif
#ifndef USE_GLL
#define USE_GLL 0
#endif

// async global->LDS, 16B per lane. LDS dest: wave-uniform base + lane*16.
__device__ __forceinline__ void gll16(const u16* g, u16* l){
#if USE_GLL
  __builtin_amdgcn_global_load_lds(
      (const __attribute__((address_space(1))) unsigned int*)(const void*)g,
      (__attribute__((address_space(3))) unsigned int*)(void*)l, 16, 0, 0);
#else
  uint4 v = *(const uint4*)g;
  *(uint4*)l = v;
#endif
}

__global__ __launch_bounds__(256) void kzero(int* p, int n){
  int i = blockIdx.x * 256 + threadIdx.x;
  if (i < n) p[i] = 0;
}

// x f32 -> xb bf16 (padded rows zeroed)
__global__ __launch_bounds__(256) void kcvt(const float* __restrict__ x,
                                            u16* __restrict__ xb){
  int i = blockIdx.x * 256 + threadIdx.x;     // 4 elems per thread
  if (i >= NPAD*HIDD/4) return;
  int base = i * 4;
  uint2 o = make_uint2(0u, 0u);
  if (base < NN*HIDD) {
    float4 v = *(const float4*)(x + base);
    o = make_uint2(pack2(v.x,v.y), pack2(v.z,v.w));
  }
  *(uint2*)(xb + base) = o;
}

// ---------------- CSR build (once per launch) ----------------
__global__ __launch_bounds__(256) void khist(const int* __restrict__ ei, int* __restrict__ counts){
  int e = blockIdx.x * 256 + threadIdx.x;
  if (e < EE) atomicAdd(&counts[ei[EE + e]], 1);
}

__global__ __launch_bounds__(256) void kscanA(const int* __restrict__ counts, int* __restrict__ bsum){
  __shared__ int sh[256];
  int t = threadIdx.x, i = blockIdx.x * 256 + t;
  sh[t] = (i < NN) ? counts[i] : 0;
  __syncthreads();
  #pragma unroll
  for (int off = 128; off; off >>= 1) {
    if (t < off) sh[t] += sh[t + off];
    __syncthreads();
  }
  if (t == 0) bsum[blockIdx.x] = sh[0];
}

__global__ __launch_bounds__(256) void kscanB(int* __restrict__ bsum, int nb){
  __shared__ int sh[256];
  int t = threadIdx.x;
  int v = (t < nb) ? bsum[t] : 0;
  sh[t] = v;
  __syncthreads();
  #pragma unroll
  for (int off = 1; off < 256; off <<= 1) {
    int a = (t >= off) ? sh[t - off] : 0;
    __syncthreads();
    sh[t] += a;
    __syncthreads();
  }
  if (t < nb) bsum[t] = sh[t] - v;   // exclusive
}

__global__ __launch_bounds__(256) void kscanC(const int* __restrict__ counts,
                                              const int* __restrict__ bsum,
                                              int* __restrict__ rowptr){
  __shared__ int sh[256];
  int t = threadIdx.x, i = blockIdx.x * 256 + t;
  int v = (i < NN) ? counts[i] : 0;
  sh[t] = v;
  __syncthreads();
  #pragma unroll
  for (int off = 1; off < 256; off <<= 1) {
    int a = (t >= off) ? sh[t - off] : 0;
    __syncthreads();
    sh[t] += a;
    __syncthreads();
  }
  if (i <= NN) rowptr[i] = bsum[blockIdx.x] + sh[t] - v;
}

__global__ __launch_bounds__(256) void kscatter(const int* __restrict__ ei,
                                                const float* __restrict__ ea,
                                                const int* __restrict__ rowptr,
                                                int* __restrict__ fill,
                                                int* __restrict__ csr_src,
                                                float* __restrict__ csr_ea){
  int e = blockIdx.x * 256 + threadIdx.x;
  if (e >= EE) return;
  int d = ei[EE + e];
  int pos = rowptr[d] + atomicAdd(&fill[d], 1);
  csr_src[pos] = ei[e];
  csr_ea[pos]  = ea[e];
}

// ---------------- per-layer weight prep -----------------
// Wt[1536][128] bf16 (transposed [Wq|Wk|Wv]), Wpt[128][512] bf16, bias_cat[1536]
__global__ __launch_bounds__(256) void kprep(
    const float* __restrict__ Wq, const float* __restrict__ Wk,
    const float* __restrict__ Wv,
    const float* __restrict__ bq, const float* __restrict__ bk,
    const float* __restrict__ bv,
    const float* __restrict__ Wp,
    u16* __restrict__ Wt, u16* __restrict__ Wpt, float* __restrict__ bias_cat)
{
  int id = blockIdx.x * 256 + threadIdx.x;
  if (id < 1536*128) {
    int n = id >> 7, k = id & 127;
    int m = n >> 9, nc = n & 511;
    const float* W = (m==0)?Wq:(m==1)?Wk:Wv;
    Wt[id] = f2bf(W[(size_t)k*HCC + nc]);
  } else if (id < 1536*128 + 128*512) {
    int j = id - 1536*128;
    int n = j >> 9, k = j & 511;
    Wpt[j] = f2bf(Wp[(size_t)k*HIDD + n]);
  } else if (id < 1536*128 + 128*512 + 1536) {
    int n = id - (1536*128 + 128*512);
    int m = n >> 9, nc = n & 511;
    const float* b = (m==0)?bq:(m==1)?bk:bv;
    bias_cat[n] = b[nc];
  }
}

// kskp2 (MFMA): Wskt[b][a] = sum_j Wpt[b][j]*Wsk[a][j]  (= (Wsk@Wp)^T, bf16)
__global__ __launch_bounds__(256) void kskp2(
    const float* __restrict__ Wsk, const u16* __restrict__ Wpt,
    u16* __restrict__ Wskt)
{
  const int t = threadIdx.x;
  const int wave = t >> 6, lane = t & 63;
  const int lo = lane & 15, hi = lane >> 4;
  const int wr = wave >> 1, wc = wave & 1;
  const int b0 = blockIdx.x * 64 + wr * 32;
  const int a0 = blockIdx.y * 32 + wc * 16;

  fx4 acc[2] = {};
  #pragma unroll
  for (int kk = 0; kk < 16; ++kk) {
    const float* wp = Wsk + (size_t)(a0 + lo)*HCC + kk*32 + hi*8;
    float4 u = *(const float4*)(wp);
    float4 w = *(const float4*)(wp + 4);
    bfcvt bc;
    bc.u = make_uint4(pack2(u.x,u.y), pack2(u.z,u.w),
                      pack2(w.x,w.y), pack2(w.z,w.w));
    #pragma unroll
    for (int fr = 0; fr < 2; ++fr) {
      bfrag af = *(const bfrag*)(Wpt + (size_t)(b0 + fr*16 + lo)*HCC + kk*32 + hi*8);
      acc[fr] = __builtin_amdgcn_mfma_f32_16x16x32_bf16(af, bc.f, acc[fr], 0, 0, 0);
    }
  }
  #pragma unroll
  for (int fr = 0; fr < 2; ++fr)
    #pragma unroll
    for (int j = 0; j < 4; ++j)
      Wskt[(size_t)(b0 + fr*16 + hi*4 + j)*128 + a0 + lo] = f2bf(acc[fr][j]);
}

// kbpe: bpe[c] = bp[c] + sum_j bsk[j]*Wp[j][c]   (grid 4, parallel-reduced)
__global__ __launch_bounds__(256) void kbpe(
    const float* __restrict__ bsk, const float* __restrict__ Wp,
    const float* __restrict__ bp, float* __restrict__ bpe)
{
  __shared__ float part[8][32];
  const int c = blockIdx.x * 32 + (threadIdx.x & 31);
  const int seg = threadIdx.x >> 5;          // 0..7, 64 j's each
  float s = 0.f;
  #pragma unroll
  for (int j = 0; j < 64; ++j)
    s += bsk[seg*64 + j] * Wp[(size_t)(seg*64 + j)*HIDD + c];
  part[seg][threadIdx.x & 31] = s;
  __syncthreads();
  if (seg == 0) {
    float tot = bp[c];
    #pragma unroll
    for (int k = 0; k < 8; ++k) tot += part[k][threadIdx.x & 31];
    bpe[c] = tot;
  }
}

// K1: qkvs[N, 0..1536) = bf16( xb[N,128] @ Wt^T + bias )
// 128x128 tile/block, 4 waves (64x64), BK=32 x 4 steps double-buffered,
// stride-132 epilogue, bijective XCD-chunked swizzle.
__global__ __launch_bounds__(256) void k1_mfma(
    const u16* __restrict__ xb, const u16* __restrict__ Wt,
    const float* __restrict__ bias, u16* __restrict__ qkvs)
{
  __shared__ u16 lds[16896];
  const int t = threadIdx.x;
  const int wave = t >> 6, lane = t & 63;
  const int lo = lane & 15, hi = lane >> 4;
  const int wr = wave >> 1, wc = wave & 1;

  int b = blockIdx.x;
  const int qq = 4692/8, rr = 4692%8;     // 586, 4
  int xcd = b & 7, slot = b >> 3;
  int wgid = (xcd < rr ? xcd*(qq+1) : rr*(qq+1) + (xcd-rr)*qq) + slot;
  const int rb = (wgid / 12) * 128;
  const int cb = (wgid % 12) * 128;

  auto STAGE = [&](int buf, int kk){
    #pragma unroll
    for (int half = 0; half < 2; ++half) {
      int c = wave*64 + lane + half*256;
      int row = c >> 2, seg = c & 3;
      gll16(xb + (size_t)(rb + row)*HIDD + kk*32 + seg*8,
            &lds[buf*4096 + (wave*64 + half*256)*8]);
    }
    #pragma unroll
    for (int half = 0; half < 2; ++half) {
      int c = wave*64 + lane + half*256;
      int row = c >> 2, seg = c & 3;
      gll16(Wt + (size_t)(cb + row)*HIDD + kk*32 + seg*8,
            &lds[8192 + buf*4096 + (wave*64 + half*256)*8]);
    }
  };

#if !USE_GLL
  auto STAGE_REG = [&](int buf, int kk){
    #pragma unroll
    for (int half = 0; half < 2; ++half) {
      int c = wave*64 + lane + half*256;
      int row = c >> 2, seg = c & 3;
      uint4 v = *(const uint4*)(xb + (size_t)(rb + row)*HIDD + kk*32 + seg*8);
      *(uint4*)&lds[buf*4096 + c*8] = v;
      uint4 w = *(const uint4*)(Wt + (size_t)(cb + row)*HIDD + kk*32 + seg*8);
      *(uint4*)&lds[8192 + buf*4096 + c*8] = w;
    }
  };
#define DO_STAGE STAGE_REG
#else
#define DO_STAGE STAGE
#endif

  fx4 acc[4][4] = {};

  DO_STAGE(0, 0);
  __syncthreads();
  #pragma unroll
  for (int kk = 0; kk < 4; ++kk) {
    const int buf = kk & 1;
    if (kk < 3) DO_STAGE(buf ^ 1, kk + 1);
    bfrag a[4], b2[4];
    #pragma unroll
    for (int fr = 0; fr < 4; ++fr)
      a[fr] = *(const bfrag*)&lds[buf*4096 + (wr*64 + fr*16 + lo)*32 + hi*8];
    #pragma unroll
    for (int fc = 0; fc < 4; ++fc)
      b2[fc] = *(const bfrag*)&lds[8192 + buf*4096 + (wc*64 + fc*16 + lo)*32 + hi*8];
    #pragma unroll
    for (int fr = 0; fr < 4; ++fr)
      #pragma unroll
      for (int fc = 0; fc < 4; ++fc)
        acc[fr][fc] = __builtin_amdgcn_mfma_f32_16x16x32_bf16(a[fr], b2[fc], acc[fr][fc], 0, 0, 0);
    __syncthreads();
  }

  float bb[4];
  #pragma unroll
  for (int fc = 0; fc < 4; ++fc) bb[fc] = bias[cb + wc*64 + fc*16 + lo];
  #pragma unroll
  for (int fr = 0; fr < 4; ++fr)
    #pragma unroll
    for (int fc = 0; fc < 4; ++fc)
      #pragma unroll
      for (int j = 0; j < 4; ++j)
        lds[(size_t)(wr*64 + fr*16 + hi*4 + j)*132 + wc*64 + fc*16 + lo]
            = f2bf(acc[fr][fc][j] + bb[fc]);
  __syncthreads();

  #pragma unroll
  for (int i = 0; i < 8; ++i) {
    int f = t + 256*i;
    int row = f >> 4, seg = f & 15;
    if (rb + row < NN)
      *(uint4*)(qkvs + (size_t)(rb+row)*QS + cb + seg*8) = *(uint4*)&lds[(size_t)row*132 + seg*8];
  }
}

// K23: fused edge attention per dst node (one wave per node).
__global__ __launch_bounds__(256) void k23_fused(
    u16* __restrict__ qkvs, const int* __restrict__ rowptr,
    const int* __restrict__ csr_src, const float* __restrict__ csr_ea,
    const float* __restrict__ We)
{
  int wave = threadIdx.x >> 6, lane = threadIdx.x & 63;
  int n = blockIdx.x * 4 + wave;
  if (n >= NN) return;
  int h = lane >> 4, c0 = (lane & 15) * 8;

  uint4 qa = *(const uint4*)(qkvs + (size_t)n*QS + h*CCC + c0);
  float qf[8] = {bfl(qa.x),bfh(qa.x),bfl(qa.y),bfh(qa.y),
                 bfl(qa.z),bfh(qa.z),bfl(qa.w),bfh(qa.w)};
  float4 w0 = *(const float4*)(We + h*CCC + c0);
  float4 w1 = *(const float4*)(We + h*CCC + c0 + 4);
  float wf[8] = {w0.x,w0.y,w0.z,w0.w,w1.x,w1.y,w1.z,w1.w};

  float qw = qf[0]*wf[0]+qf[1]*wf[1]+qf[2]*wf[2]+qf[3]*wf[3]
           + qf[4]*wf[4]+qf[5]*wf[5]+qf[6]*wf[6]+qf[7]*wf[7];
  #pragma unroll
  for (int off = 8; off; off >>= 1) qw += __shfl_xor(qw, off);

  int beg = rowptr[n], end = rowptr[n+1];
  float accv[8] = {};
  float accp = 0.f, accw = 0.f;

  for (int i = beg; i < end; ++i) {
    int src = csr_src[i];
    float eav = csr_ea[i];
    uint4 ka = *(const uint4*)(qkvs + (size_t)src*QS + 512 + h*CCC + c0);
    float s = qf[0]*bfl(ka.x) + qf[1]*bfh(ka.x)
            + qf[2]*bfl(ka.y) + qf[3]*bfh(ka.y)
            + qf[4]*bfl(ka.z) + qf[5]*bfh(ka.z)
            + qf[6]*bfl(ka.w) + qf[7]*bfh(ka.w);
    #pragma unroll
    for (int off = 8; off; off >>= 1) s += __shfl_xor(s, off);
    float p = expf((s + eav * qw) * SCALE);
    uint4 va = *(const uint4*)(qkvs + (size_t)src*QS + 1024 + h*CCC + c0);
    accv[0] += p*bfl(va.x); accv[1] += p*bfh(va.x);
    accv[2] += p*bfl(va.y); accv[3] += p*bfh(va.y);
    accv[4] += p*bfl(va.z); accv[5] += p*bfh(va.z);
    accv[6] += p*bfl(va.w); accv[7] += p*bfh(va.w);
    accp += p; accw += p*eav;
  }

  float inv = 1.f / (accp + 1e-16f);
  float se  = accw * inv;
  u16* ap = qkvs + (size_t)n*QS + 1536 + h*CCC + c0;
  *(uint4*)ap = make_uint4(
    pack2(accv[0]*inv+se*wf[0], accv[1]*inv+se*wf[1]),
    pack2(accv[2]*inv+se*wf[2], accv[3]*inv+se*wf[3]),
    pack2(accv[4]*inv+se*wf[4], accv[5]*inv+se*wf[5]),
    pack2(accv[6]*inv+se*wf[6], accv[7]*inv+se*wf[7]));
}

// K4 (fused K=640, 32-row tiles): y = elu([conv|xb]@[Wpt;Wskt]+bpe) + xb ; LN
// 32x128 tile, 4 waves 2x2 (16x64 each, acc 4), BK=32 x 20 steps dbuf.
// LDS 20.5KB (staging reused as yt for the epilogue); coalesced stores;
// bf16 xb_out always, f32 x_out only when last=1.
__global__ __launch_bounds__(256) void k4_mfma(
    const u16* __restrict__ qkvs, const u16* __restrict__ xb_in,
    const u16* __restrict__ Wpt, const u16* __restrict__ Wskt,
    const float* __restrict__ bpe,
    const float* __restrict__ gamma, const float* __restrict__ beta,
    float* __restrict__ x_out, u16* __restrict__ xb_out, int last)
{
  __shared__ __align__(16) u16 lds[10240];   // A [2][1024] at 0, B [2][4096] at 2048
  float* yt   = (float*)lds;                 // epilogue: [32][132] f32 (16896B)
  float* mu_s = (float*)&lds[8448];          // byte 16896
  float* rs_s = (float*)&lds[8512];          // byte 17024
  const int t = threadIdx.x;
  const int wave = t >> 6, lane = t & 63;
  const int lo = lane & 15, hi = lane >> 4;
  const int wr = wave >> 1, wc = wave & 1;
  const int rb = blockIdx.x * 32;

  auto STAGE = [&](int buf, int kk){
    if (wave < 2) {                           // A: 128 chunks (32 rows x 4 segs)
      int c = wave*64 + lane;
      int row = c >> 2, seg = c & 3;
      const u16* src = (kk < 16)
        ? qkvs + (size_t)(rb + row)*QS + 1536 + kk*32 + seg*8
        : xb_in + (size_t)(rb + row)*HIDD + (kk-16)*32 + seg*8;
#if USE_GLL
      gll16(src, &lds[buf*1024 + (wave*64)*8]);
#else
      *(uint4*)&lds[buf*1024 + c*8] = *(const uint4*)src;
#endif
    }
    #pragma unroll
    for (int half = 0; half < 2; ++half) {    // B: 512 chunks (128 cols x 4 segs)
      int c = wave*64 + lane + half*256;
      int col = c >> 2, seg = c & 3;
      const u16* src = (kk < 16)
        ? Wpt  + (size_t)col*512 + kk*32 + seg*8
        : Wskt + (size_t)col*128 + (kk-16)*32 + seg*8;
#if USE_GLL
      gll16(src, &lds[2048 + buf*4096 + (wave*64 + half*256)*8]);
#else
      *(uint4*)&lds[2048 + buf*4096 + c*8] = *(const uint4*)src;
#endif
    }
  };

  fx4 acc[4] = {};

  STAGE(0, 0);
  __syncthreads();
  #pragma unroll
  for (int kk = 0; kk < 20; ++kk) {
    const int buf = kk & 1;
    if (kk < 19) STAGE(buf ^ 1, kk + 1);
    bfrag a = *(const bfrag*)&lds[buf*1024 + (wr*16 + lo)*32 + hi*8];
    bfrag b[4];
    #pragma unroll
    for (int fc = 0; fc < 4; ++fc)
      b[fc] = *(const bfrag*)&lds[2048 + buf*4096 + (wc*64 + fc*16 + lo)*32 + hi*8];
    #pragma unroll
    for (int fc = 0; fc < 4; ++fc)
      acc[fc] = __builtin_amdgcn_mfma_f32_16x16x32_bf16(a, b[fc], acc[fc], 0, 0, 0);
    __syncthreads();
  }

  // epilogue: bias + ELU + bf16 residual (registers), then yt LDS for LN+stores
  float y[4][4];
  #pragma unroll
  for (int fc = 0; fc < 4; ++fc) {
    int col = wc*64 + fc*16 + lo;
    float bb = bpe[col];
    #pragma unroll
    for (int j = 0; j < 4; ++j) {
      int row = rb + wr*16 + hi*4 + j;
      float v = acc[fc][j] + bb;
      v = v > 0.f ? v : expm1f(v);
      float xv = (row < NN) ? bf1(xb_in[(size_t)row*HIDD + col]) : 0.f;
      y[fc][j] = xv + v;
    }
  }
  #pragma unroll
  for (int fc = 0; fc < 4; ++fc)
    #pragma unroll
    for (int j = 0; j < 4; ++j)
      yt[(size_t)(wr*16 + hi*4 + j)*132 + wc*64 + fc*16 + lo] = y[fc][j];
  __syncthreads();

  // row stats: 8 threads per row, 16 cols each
  {
    int r = t >> 3, seg = t & 7;
    float s = 0.f, s2 = 0.f;
    #pragma unroll
    for (int j = 0; j < 16; ++j) {
      float v = yt[(size_t)r*132 + seg*16 + j];
      s += v; s2 += v*v;
    }
    #pragma unroll
    for (int off = 4; off; off >>= 1) { s += __shfl_xor(s, off); s2 += __shfl_xor(s2, off); }
    if (seg == 0) {
      float mu = s * (1.f/128.f);
      float var = s2 * (1.f/128.f) - mu*mu;
      mu_s[r] = mu;
      rs_s[r] = rsqrtf(var + 1e-5f);
    }
  }
  __syncthreads();

  // normalize + coalesced stores (bf16 always; f32 only on last layer)
  #pragma unroll
  for (int i = 0; i < 4; ++i) {
    int f = t + 256*i;               // 1024 float4 = 32 rows x 128 cols
    int r = f >> 5, c4 = (f & 31) * 4;
    int row = rb + r;
    if (row >= NN) continue;
    float mu = mu_s[r], rs = rs_s[r];
    float4 g  = *(const float4*)(gamma + c4);
    float4 bt = *(const float4*)(beta + c4);
    float4 yv = *(float4*)&yt[(size_t)r*132 + c4];
    float4 o = make_float4((yv.x-mu)*rs*g.x + bt.x, (yv.y-mu)*rs*g.y + bt.y,
                           (yv.z-mu)*rs*g.z + bt.z, (yv.w-mu)*rs*g.w + bt.w);
    *(uint2*)(xb_out + (size_t)row*HIDD + c4) = make_uint2(pack2(o.x,o.y), pack2(o.z,o.w));
    if (last) *(float4*)(x_out + (size_t)row*HIDD + c4) = o;
  }
}

extern "C" void kernel_launch(void* const* d_in, const int* in_sizes, int n_in,
                              void* d_out, int out_size, void* d_ws, size_t ws_size,
                              hipStream_t stream)
{
  const float* x    = (const float*)d_in[0];
  const int*   ei   = (const int*)d_in[1];
  const float* ea   = (const float*)d_in[2];
  const float* Wq   = (const float*)d_in[3];
  const float* bq   = (const float*)d_in[4];
  const float* Wk   = (const float*)d_in[5];
  const float* bk   = (const float*)d_in[6];
  const float* Wv   = (const float*)d_in[7];
  const float* bv   = (const float*)d_in[8];
  const float* We   = (const float*)d_in[9];
  const float* Wsk  = (const float*)d_in[10];
  const float* bsk  = (const float*)d_in[11];
  const float* Wp   = (const float*)d_in[12];
  const float* bp   = (const float*)d_in[13];
  const float* gamma= (const float*)d_in[14];
  const float* beta = (const float*)d_in[15];

  char* wsb = (char*)d_ws;
  size_t off = 0;
  auto alloc = [&](size_t bytes) -> void* {
    void* p = wsb + off;
    off += (bytes + 255) & ~(size_t)255;
    return p;
  };
  u16*   qkvs    = (u16*)  alloc((size_t)NPAD*QS*2);   // 205.5 MB (q|k|v|conv, padded)
  u16*   xb      = (u16*)  alloc((size_t)NPAD*HIDD*2); // 12.85 MB bf16 x
  int*   rowptr  = (int*)  alloc((size_t)(NN+1)*4);
  int*   counts  = (int*)  alloc((size_t)NN*4);
  int*   fill    = (int*)  alloc((size_t)NN*4);
  int*   bsum    = (int*)  alloc((size_t)256*4);
  int*   csr_src = (int*)  alloc((size_t)EE*4);
  float* csr_ea  = (float*)alloc((size_t)EE*4);
  u16*   Wt      = (u16*)  alloc((size_t)1536*128*2);
  u16*   Wpt     = (u16*)  alloc((size_t)128*512*2);
  u16*   Wskt    = (u16*)  alloc((size_t)128*128*2);
  float* biasc   = (float*)alloc((size_t)1536*4);
  float* bpe     = (float*)alloc((size_t)128*4);
  float* xio     = (float*)d_out;

  const int gn  = (NN + 255)/256;     // 196
  const int ge  = (EE + 255)/256;
  const int gp  = (1536*128 + 128*512 + 1536 + 255)/256;
  const int gc  = (NPAD*HIDD/4 + 255)/256;   // kcvt
  const int g1  = 12 * ((NN + 127)/128);     // 4692 blocks, swizzled in-kernel
  const dim3 gsk(2, 4);               // kskp2 tiles
  const int g23 = (NN + 3)/4;
  const int g4  = NPAD/32;            // 1568 blocks of 32 rows

  // ---- CSR build (graph constant across layers) + x bf16 ----
  kzero<<<gn, 256, 0, stream>>>(counts, NN);
  kzero<<<gn, 256, 0, stream>>>(fill, NN);
  khist<<<ge, 256, 0, stream>>>(ei, counts);
  kscanA<<<gn, 256, 0, stream>>>(counts, bsum);
  kscanB<<<1, 256, 0, stream>>>(bsum, gn);
  kscanC<<<gn, 256, 0, stream>>>(counts, bsum, rowptr);
  kscatter<<<ge, 256, 0, stream>>>(ei, ea, rowptr, fill, csr_src, csr_ea);
  kcvt<<<gc, 256, 0, stream>>>(x, xb);

  for (int l = 0; l < LLL; ++l) {
    const float* Wq_l  = Wq  + (size_t)l*HIDD*HCC;
    const float* Wk_l  = Wk  + (size_t)l*HIDD*HCC;
    const float* Wv_l  = Wv  + (size_t)l*HIDD*HCC;
    const float* Wsk_l = Wsk + (size_t)l*HIDD*HCC;
    const float* bq_l  = bq  + (size_t)l*HCC;
    const float* bk_l  = bk  + (size_t)l*HCC;
    const float* bv_l  = bv  + (size_t)l*HCC;
    const float* bsk_l = bsk + (size_t)l*HCC;
    const float* We_l  = We  + (size_t)l*HCC;
    const float* Wp_l  = Wp  + (size_t)l*HCC*HIDD;
    const float* bp_l  = bp  + (size_t)l*HIDD;
    const float* g_l   = gamma + (size_t)l*HIDD;
    const float* b_l   = beta  + (size_t)l*HIDD;

    kprep<<<gp, 256, 0, stream>>>(Wq_l, Wk_l, Wv_l, bq_l, bk_l, bv_l,
                                  Wp_l, Wt, Wpt, biasc);
    kskp2<<<gsk, 256, 0, stream>>>(Wsk_l, Wpt, Wskt);
    kbpe<<<4, 256, 0, stream>>>(bsk_l, Wp_l, bp_l, bpe);
    k1_mfma<<<g1, 256, 0, stream>>>(xb, Wt, biasc, qkvs);
    k23_fused<<<g23, 256, 0, stream>>>(qkvs, rowptr, csr_src, csr_ea, We_l);
    k4_mfma<<<g4, 256, 0, stream>>>(qkvs, xb, Wpt, Wskt, bpe, g_l, b_l,
                                    xio, xb, (l == LLL-1) ? 1 : 0);
  }
}